// Round 8
// baseline (162.154 us; speedup 1.0000x reference)
//
#include <hip/hip_runtime.h>
#include <hip/hip_bf16.h>
#include <stdint.h>

// CapsuleLayer dynamic routing v8.
// b_r[b,j,i] = sum_k u_hat[b,j,i,k] * Vacc[b,j,k]  (Vacc = sum of prior v's)
// Lane = (j:0-31 | kh bit5). Thread owns 1 j, 8 k's, NB=4 batches (halves
// per-route LDS W-read volume vs NB=2: the LDS pipe was ~70% busy in v6).
// v7's deeper vmcnt pipeline regressed (lost 3rd WG/CU); v6's 1-barrier
// double-buffer is already distance-1 covered -> reverted to it.
// W_i tile (16KB) via global_load_lds, pre-swizzled source, double-buffered
// (proven: FETCH ~13MB, conflicts 0). Epilogue: LDS transpose + COALESCED
// atomics (64 contiguous addrs/instr; v6-proven, WRITE = atomic footprint).

#define I_TILE  12
#define NSLICE  96                    // 1152/12; grid 8*96 = 768 = 3 WG/CU
#define WJ      (1152 * 128)          // floats between j planes

template<int R>
__global__ __launch_bounds__(256)
void caps_route(const float* __restrict__ x,     // [128,1152,8]
                const float* __restrict__ W,     // [32,1152,16,8]
                const float* __restrict__ Vacc,  // [128,32,16]
                float* __restrict__ s)           // [128,32,16] zeroed
{
    __shared__ float Wt[2][4096];     // 2 x 16KB W_i tiles; dead after loop
    __shared__ float xs[16 * 96];     // [bl][12*8], 6KB

    const int tid  = threadIdx.x;
    const int lane = tid & 63;
    const int wv   = tid >> 6;        // wave 0..3
    const int j    = lane & 31;
    const int kh   = lane >> 5;       // k half
    const int bg   = blockIdx.x / NSLICE;   // 0..7
    const int sl   = blockIdx.x % NSLICE;   // 0..95
    const int i0   = sl * I_TILE;
    const int b0   = bg * 16 + wv * 4;      // this wave's 4 batches

    // ---- pre-swizzled global sources for global_load_lds (v4-proven) ----
    // LDS byte q = (wv*4+t)*1024 + lane*16 (linear dest). Inverse swizzle:
    // row rr=q>>8, cb=(q&255)^((rr&15)<<4); js=rr&31; c=(rr>>5)*64+cb/4.
    const float* wsrc[4];
    #pragma unroll
    for (int t = 0; t < 4; ++t) {
        const int q  = (wv * 4 + t) * 1024 + lane * 16;
        const int rr = q >> 8;
        const int cb = (q & 255) ^ ((rr & 15) << 4);
        const int js = rr & 31;
        const int c  = (rr >> 5) * 64 + (cb >> 2);
        wsrc[t] = W + (size_t)js * WJ + c;
    }

    auto stage = [&](int buf, int i) {
        #pragma unroll
        for (int t = 0; t < 4; ++t)
            __builtin_amdgcn_global_load_lds(
                (const __attribute__((address_space(1))) uint32_t*)
                    (wsrc[t] + (size_t)i * 128),
                (__attribute__((address_space(3))) uint32_t*)
                    &Wt[buf][(wv * 4 + t) * 256],
                16, 0, 0);
    };

    stage(0, i0);

    // ---- x slice -> LDS (16 batches x 24 float4, coalesced) ----
    for (int cf = tid; cf < 384; cf += 256) {
        const int bl = cf / 24;
        const int rm = cf - bl * 24;
        float4 v = *reinterpret_cast<const float4*>(
            x + ((size_t)(bg * 16 + bl) * 1152 + i0) * 8 + rm * 4);
        *reinterpret_cast<float4*>(xs + bl * 96 + rm * 4) = v;
    }

    // Vacc fragments, prescaled to log2 domain
    float Vr[4][8];
    if (R > 0) {
        #pragma unroll
        for (int bb = 0; bb < 4; ++bb) {
            const float* vp =
                Vacc + ((size_t)(b0 + bb) * 32 + j) * 16 + kh * 8;
            const float4 va = *reinterpret_cast<const float4*>(vp);
            const float4 vb = *reinterpret_cast<const float4*>(vp + 4);
            Vr[bb][0] = va.x * 1.44269504f; Vr[bb][1] = va.y * 1.44269504f;
            Vr[bb][2] = va.z * 1.44269504f; Vr[bb][3] = va.w * 1.44269504f;
            Vr[bb][4] = vb.x * 1.44269504f; Vr[bb][5] = vb.y * 1.44269504f;
            Vr[bb][6] = vb.z * 1.44269504f; Vr[bb][7] = vb.w * 1.44269504f;
        }
    }

    float sacc[4][8];
    #pragma unroll
    for (int bb = 0; bb < 4; ++bb)
        #pragma unroll
        for (int kk = 0; kk < 8; ++kk) sacc[bb][kk] = 0.0f;

    __syncthreads();   // drains vmcnt: first W tile + xs ready

    const int sw = (j & 15) << 4;    // read-side swizzle (row = lane)

    for (int ii = 0; ii < I_TILE; ++ii) {
        const int cur = ii & 1;
        if (ii + 1 < I_TILE) stage(cur ^ 1, i0 + ii + 1);

        // x fragments: wave-uniform LDS address -> broadcast, conflict-free
        float4 xa[4], xb[4];
        #pragma unroll
        for (int bb = 0; bb < 4; ++bb) {
            const float* xp = xs + (wv * 4 + bb) * 96 + ii * 8;
            xa[bb] = *reinterpret_cast<const float4*>(xp);
            xb[bb] = *reinterpret_cast<const float4*>(xp + 4);
        }

        const char* lbase =
            reinterpret_cast<const char*>(&Wt[cur][0]) + lane * 256;

        float u[4][8];
        #pragma unroll
        for (int kk = 0; kk < 8; ++kk) {
            const float4 w0 = *reinterpret_cast<const float4*>(
                lbase + ((kk * 32) ^ sw));
            const float4 w1 = *reinterpret_cast<const float4*>(
                lbase + ((kk * 32 + 16) ^ sw));
            #pragma unroll
            for (int bb = 0; bb < 4; ++bb) {
                float acc;
                acc = w0.x * xa[bb].x;
                acc = fmaf(w0.y, xa[bb].y, acc);
                acc = fmaf(w0.z, xa[bb].z, acc);
                acc = fmaf(w0.w, xa[bb].w, acc);
                acc = fmaf(w1.x, xb[bb].x, acc);
                acc = fmaf(w1.y, xb[bb].y, acc);
                acc = fmaf(w1.z, xb[bb].z, acc);
                acc = fmaf(w1.w, xb[bb].w, acc);
                u[bb][kk] = acc;
            }
        }

        if (R == 0) {
            #pragma unroll
            for (int bb = 0; bb < 4; ++bb)
                #pragma unroll
                for (int kk = 0; kk < 8; ++kk)
                    sacc[bb][kk] = fmaf(0.03125f, u[bb][kk], sacc[bb][kk]);
        } else {
            // two paired-softmax rounds: round r does batches {2r, 2r+1}
            #pragma unroll
            for (int r2 = 0; r2 < 2; ++r2) {
                const int bA = 2 * r2, bB = 2 * r2 + 1;
                float p0 = u[bA][0] * Vr[bA][0];
                float p1 = u[bB][0] * Vr[bB][0];
                #pragma unroll
                for (int kk = 1; kk < 8; ++kk) {
                    p0 = fmaf(u[bA][kk], Vr[bA][kk], p0);
                    p1 = fmaf(u[bB][kk], Vr[bB][kk], p1);
                }
                p0 += __shfl_xor(p0, 32);
                p1 += __shfl_xor(p1, 32);
                // kh=0 half handles bA, kh=1 half bB
                const float pq = kh ? p1 : p0;
                const float e  = exp2f(pq);      // no max-subtract: |pq| small
                float den = e;
                den += __shfl_xor(den, 1);
                den += __shfl_xor(den, 2);
                den += __shfl_xor(den, 4);
                den += __shfl_xor(den, 8);
                den += __shfl_xor(den, 16);
                const float cf_own = e * __builtin_amdgcn_rcpf(den);
                const float cf_oth = __shfl_xor(cf_own, 32);
                const float cfA = kh ? cf_oth : cf_own;
                const float cfB = kh ? cf_own : cf_oth;
                #pragma unroll
                for (int kk = 0; kk < 8; ++kk) {
                    sacc[bA][kk] = fmaf(cfA, u[bA][kk], sacc[bA][kk]);
                    sacc[bB][kk] = fmaf(cfB, u[bB][kk], sacc[bB][kk]);
                }
            }
        }
        __syncthreads();   // prefetch landed (vmcnt0) + reads of cur done
    }

    // ---- epilogue: per-wave LDS transpose -> COALESCED atomics ----
    // All Wt reads finished (final loop barrier). Each wave owns a private
    // 8KB region spanning Wt[0..1] (32KB total), so no further barrier.
    // Store swizzle k' = k ^ ((j>>1)&15): 2-way max on write and read.
    {
        float* ep = &Wt[0][0] + wv * 2048;
        #pragma unroll
        for (int bb = 0; bb < 4; ++bb)
            #pragma unroll
            for (int kk = 0; kk < 8; ++kk)
                ep[bb * 512 + j * 16 + ((kh * 8 + kk) ^ ((j >> 1) & 15))] =
                    sacc[bb][kk];

        float* sg = s + (size_t)b0 * 512;   // flat (b0..b0+3, j, k)
        #pragma unroll
        for (int c = 0; c < 32; ++c) {
            const int m   = c * 64 + lane;      // flat (bb, j, k)
            const int bb2 = m >> 9;
            const int j2  = (m >> 4) & 31;
            const int k2  = m & 15;
            const float v = ep[bb2 * 512 + j2 * 16 + (k2 ^ ((j2 >> 1) & 15))];
            atomicAdd(&sg[m], v);               // 64 contiguous addrs/instr
        }
    }
}

// MODE 0: Vacc = v, zero s;  MODE 1: Vacc += v, zero s;  MODE 2: out = v
template<int MODE>
__global__ __launch_bounds__(256)
void caps_squash(float* __restrict__ s,
                 float* __restrict__ Vacc,
                 float* __restrict__ out)
{
    const int t = blockIdx.x * 256 + threadIdx.x;   // (b,j,k), k fastest
    const float sv = s[t];
    float p = sv * sv;
    p += __shfl_xor(p, 1);
    p += __shfl_xor(p, 2);
    p += __shfl_xor(p, 4);
    p += __shfl_xor(p, 8);
    const float scale = p / ((1.0f + p) * sqrtf(p + 1e-7f));
    const float v = scale * sv;
    if (MODE == 0)      { Vacc[t] = v;  s[t] = 0.0f; }
    else if (MODE == 1) { Vacc[t] += v; s[t] = 0.0f; }
    else                { out[t] = v; }
}

extern "C" void kernel_launch(void* const* d_in, const int* in_sizes, int n_in,
                              void* d_out, int out_size, void* d_ws, size_t ws_size,
                              hipStream_t stream)
{
    const float* x = (const float*)d_in[0];   // [128,1152,8]
    const float* W = (const float*)d_in[1];   // [32,1152,16,8]
    float* out  = (float*)d_out;              // [128,32,16]
    float* Vacc = (float*)d_ws;               // 65536 floats
    float* s    = Vacc + 65536;               // 65536 floats

    hipMemsetAsync(s, 0, (size_t)65536 * sizeof(float), stream);

    dim3 grid(8 * NSLICE);   // 768 WGs = 3/CU
    dim3 blk(256);

    caps_route<0><<<grid, blk, 0, stream>>>(x, W, Vacc, s);
    caps_squash<0><<<256, 256, 0, stream>>>(s, Vacc, out);

    caps_route<1><<<grid, blk, 0, stream>>>(x, W, Vacc, s);
    caps_squash<1><<<256, 256, 0, stream>>>(s, Vacc, out);

    caps_route<2><<<grid, blk, 0, stream>>>(x, W, Vacc, s);
    caps_squash<2><<<256, 256, 0, stream>>>(s, Vacc, out);
}

// Round 9
// 136.882 us; speedup vs baseline: 1.1846x; 1.1846x over previous
//
#include <hip/hip_runtime.h>
#include <hip/hip_bf16.h>
#include <stdint.h>

// CapsuleLayer dynamic routing v9.
// b_r[b,j,i] = sum_k u_hat[b,j,i,k] * Vacc[b,j,k]  (Vacc = sum of prior v's)
// v6 (50us route) was LDS-instruction-pipe bound: 16 of 20 ds_read_b128 per
// wave-iter were the fp32 W tile. v9 stages W as BF16 (prep kernel writes a
// pre-swizzled bf16 copy of W into d_ws once per launch) -> 8 W reads per
// wave-iter, 19KB LDS/WG, grid 1536 (~6 WG/CU). Unpack bf16->f32 = shift/and
// (cheap VALU; VALU had headroom at 47%). Softmax + coalesced-atomic
// epilogue identical to v6 (proven: conflicts 0, WRITE = atomic footprint).
// Fallback: if ws_size too small for W2 (9.4MB), run v6 fp32 path verbatim.

#define WJ (1152 * 128)

__device__ __forceinline__ uint32_t bfr(float f) {   // fp32 -> bf16 RTN-even
    uint32_t u = __float_as_uint(f);
    return (u + 0x7fffu + ((u >> 16) & 1u)) >> 16;
}

// ---- prep: W[j,i,k,l] fp32 -> W2 = per-i pre-swizzled 8KB bf16 tiles ----
// W2 uint4 index t=(i*64+r)*8+s holds (row r, phys slot s): j=r&31,
// k=(r>>5)*8+(s^(r&7)), l=0..7 packed as 4 bf16-pairs.
__global__ __launch_bounds__(256)
void caps_prep(const float* __restrict__ W, uint4* __restrict__ W2)
{
    const int t = blockIdx.x * 256 + threadIdx.x;    // (i, r, s)
    const int s = t & 7;
    const int r = (t >> 3) & 63;
    const int i = t >> 9;
    const int j = r & 31;
    const int k = ((r >> 5) << 3) + (s ^ (r & 7));
    const float* src = W + (((size_t)j * 1152 + i) * 16 + k) * 8;
    const float4 a = *reinterpret_cast<const float4*>(src);
    const float4 b = *reinterpret_cast<const float4*>(src + 4);
    uint4 o;
    o.x = bfr(a.x) | (bfr(a.y) << 16);
    o.y = bfr(a.z) | (bfr(a.w) << 16);
    o.z = bfr(b.x) | (bfr(b.y) << 16);
    o.w = bfr(b.z) | (bfr(b.w) << 16);
    W2[t] = o;
}

// ============================ bf16 route ============================
#define I_TILE  12
#define NSLICE  96                    // grid 16*96 = 1536 ~ 6 WG/CU

template<int R>
__global__ __launch_bounds__(256)
void caps_route(const uint32_t* __restrict__ W2,  // pre-swizzled bf16 tiles
                const float* __restrict__ x,      // [128,1152,8]
                const float* __restrict__ Vacc,   // [128,32,16]
                float* __restrict__ s)            // [128,32,16] zeroed
{
    __shared__ uint32_t Wt[2][2048];  // 2 x 8KB bf16 W_i tiles
    __shared__ float xs[8 * 96];      // [bl][12*8], 3KB

    const int tid  = threadIdx.x;
    const int lane = tid & 63;
    const int wv   = tid >> 6;
    const int j    = lane & 31;
    const int kh   = lane >> 5;
    const int bg   = blockIdx.x / NSLICE;   // 0..15
    const int sl   = blockIdx.x % NSLICE;   // 0..95
    const int i0   = sl * I_TILE;
    const int b0   = bg * 8 + wv * 2;

    // stage: dest linear (lane*16B), source already swizzled by prep
    auto stage = [&](int buf, int i) {
        #pragma unroll
        for (int t = 0; t < 2; ++t)
            __builtin_amdgcn_global_load_lds(
                (const __attribute__((address_space(1))) uint32_t*)
                    (W2 + (size_t)i * 2048 + (wv * 2 + t) * 256 + lane * 4),
                (__attribute__((address_space(3))) uint32_t*)
                    &Wt[buf][(wv * 2 + t) * 256], 16, 0, 0);
    };

    stage(0, i0);

    // x slice -> LDS (192 float4, coalesced)
    if (tid < 192) {
        const int bl = tid / 24;
        const int rm = tid - bl * 24;
        float4 v = *reinterpret_cast<const float4*>(
            x + ((size_t)(bg * 8 + bl) * 1152 + i0) * 8 + rm * 4);
        *reinterpret_cast<float4*>(xs + bl * 96 + rm * 4) = v;
    }

    float Vr[2][8];
    if (R > 0) {
        #pragma unroll
        for (int bb = 0; bb < 2; ++bb) {
            const float* vp = Vacc + ((size_t)(b0 + bb) * 32 + j) * 16 + kh * 8;
            const float4 va = *reinterpret_cast<const float4*>(vp);
            const float4 vb = *reinterpret_cast<const float4*>(vp + 4);
            Vr[bb][0] = va.x * 1.44269504f; Vr[bb][1] = va.y * 1.44269504f;
            Vr[bb][2] = va.z * 1.44269504f; Vr[bb][3] = va.w * 1.44269504f;
            Vr[bb][4] = vb.x * 1.44269504f; Vr[bb][5] = vb.y * 1.44269504f;
            Vr[bb][6] = vb.z * 1.44269504f; Vr[bb][7] = vb.w * 1.44269504f;
        }
    }

    float sacc[2][8];
    #pragma unroll
    for (int bb = 0; bb < 2; ++bb)
        #pragma unroll
        for (int kk = 0; kk < 8; ++kk) sacc[bb][kk] = 0.0f;

    __syncthreads();   // first tile + xs ready (barrier drains vmcnt)

    const int swq = lane & 7;     // read-side slot XOR (row = lane)

    for (int ii = 0; ii < I_TILE; ++ii) {
        const int cur = ii & 1;
        if (ii + 1 < I_TILE) stage(cur ^ 1, i0 + ii + 1);

        float4 xa[2], xb[2];
        #pragma unroll
        for (int bb = 0; bb < 2; ++bb) {
            const float* xp = xs + (wv * 2 + bb) * 96 + ii * 8;
            xa[bb] = *reinterpret_cast<const float4*>(xp);
            xb[bb] = *reinterpret_cast<const float4*>(xp + 4);
        }

        const uint32_t* lb = &Wt[cur][lane * 32];   // this lane's 128B row

        float u[2][8];
        #pragma unroll
        for (int kk = 0; kk < 8; ++kk) {
            const uint4 v = *reinterpret_cast<const uint4*>(
                lb + ((kk ^ swq) << 2));
            const float w0 = __uint_as_float(v.x << 16);
            const float w1 = __uint_as_float(v.x & 0xffff0000u);
            const float w2 = __uint_as_float(v.y << 16);
            const float w3 = __uint_as_float(v.y & 0xffff0000u);
            const float w4 = __uint_as_float(v.z << 16);
            const float w5 = __uint_as_float(v.z & 0xffff0000u);
            const float w6 = __uint_as_float(v.w << 16);
            const float w7 = __uint_as_float(v.w & 0xffff0000u);
            #pragma unroll
            for (int bb = 0; bb < 2; ++bb) {
                float acc;
                acc = w0 * xa[bb].x;
                acc = fmaf(w1, xa[bb].y, acc);
                acc = fmaf(w2, xa[bb].z, acc);
                acc = fmaf(w3, xa[bb].w, acc);
                acc = fmaf(w4, xb[bb].x, acc);
                acc = fmaf(w5, xb[bb].y, acc);
                acc = fmaf(w6, xb[bb].z, acc);
                acc = fmaf(w7, xb[bb].w, acc);
                u[bb][kk] = acc;
            }
        }

        if (R == 0) {
            #pragma unroll
            for (int bb = 0; bb < 2; ++bb)
                #pragma unroll
                for (int kk = 0; kk < 8; ++kk)
                    sacc[bb][kk] = fmaf(0.03125f, u[bb][kk], sacc[bb][kk]);
        } else {
            float p0 = u[0][0] * Vr[0][0];
            float p1 = u[1][0] * Vr[1][0];
            #pragma unroll
            for (int kk = 1; kk < 8; ++kk) {
                p0 = fmaf(u[0][kk], Vr[0][kk], p0);
                p1 = fmaf(u[1][kk], Vr[1][kk], p1);
            }
            p0 += __shfl_xor(p0, 32);
            p1 += __shfl_xor(p1, 32);
            // paired softmax: kh=0 half does batch 0, kh=1 half batch 1
            const float pq = kh ? p1 : p0;
            const float e  = exp2f(pq);          // no max-subtract: |pq| small
            float den = e;
            den += __shfl_xor(den, 1);
            den += __shfl_xor(den, 2);
            den += __shfl_xor(den, 4);
            den += __shfl_xor(den, 8);
            den += __shfl_xor(den, 16);
            const float cf_own = e * __builtin_amdgcn_rcpf(den);
            const float cf_oth = __shfl_xor(cf_own, 32);
            const float cf0 = kh ? cf_oth : cf_own;
            const float cf1 = kh ? cf_own : cf_oth;
            #pragma unroll
            for (int kk = 0; kk < 8; ++kk) {
                sacc[0][kk] = fmaf(cf0, u[0][kk], sacc[0][kk]);
                sacc[1][kk] = fmaf(cf1, u[1][kk], sacc[1][kk]);
            }
        }
        __syncthreads();
    }

    // ---- epilogue: per-wave LDS transpose -> COALESCED atomics (v6) ----
    // All Wt reads done (final loop barrier); each wave owns a private 4KB
    // region of Wt (16KB total). Swizzle k' = k ^ ((j>>1)&15).
    {
        float* ep = reinterpret_cast<float*>(&Wt[0][0]) + wv * 1024;
        #pragma unroll
        for (int bb = 0; bb < 2; ++bb)
            #pragma unroll
            for (int kk = 0; kk < 8; ++kk)
                ep[bb * 512 + j * 16 + ((kh * 8 + kk) ^ ((j >> 1) & 15))] =
                    sacc[bb][kk];

        float* sg = s + (size_t)b0 * 512;
        #pragma unroll
        for (int c = 0; c < 16; ++c) {
            const int m   = c * 64 + lane;
            const int bb2 = m >> 9;
            const int j2  = (m >> 4) & 31;
            const int k2  = m & 15;
            const float v = ep[bb2 * 512 + j2 * 16 + (k2 ^ ((j2 >> 1) & 15))];
            atomicAdd(&sg[m], v);               // 64 contiguous addrs/instr
        }
    }
}

// ==================== fp32 fallback route (v6 verbatim) ====================
#define I_TILE_F  24
#define NSLICE_F  48

template<int R>
__global__ __launch_bounds__(256)
void caps_route_f32(const float* __restrict__ x,
                    const float* __restrict__ W,
                    const float* __restrict__ Vacc,
                    float* __restrict__ s)
{
    __shared__ float Wt[2][4096];
    __shared__ float xs[8 * 192];

    const int tid  = threadIdx.x;
    const int lane = tid & 63;
    const int wv   = tid >> 6;
    const int j    = lane & 31;
    const int kh   = lane >> 5;
    const int bg   = blockIdx.x / NSLICE_F;
    const int sl   = blockIdx.x % NSLICE_F;
    const int i0   = sl * I_TILE_F;
    const int b0   = bg * 8 + wv * 2;

    const float* wsrc[4];
    #pragma unroll
    for (int t = 0; t < 4; ++t) {
        const int q  = (wv * 4 + t) * 1024 + lane * 16;
        const int rr = q >> 8;
        const int cb = (q & 255) ^ ((rr & 15) << 4);
        const int js = rr & 31;
        const int c  = (rr >> 5) * 64 + (cb >> 2);
        wsrc[t] = W + (size_t)js * WJ + c;
    }

    auto stage = [&](int buf, int i) {
        #pragma unroll
        for (int t = 0; t < 4; ++t)
            __builtin_amdgcn_global_load_lds(
                (const __attribute__((address_space(1))) uint32_t*)
                    (wsrc[t] + (size_t)i * 128),
                (__attribute__((address_space(3))) uint32_t*)
                    &Wt[buf][(wv * 4 + t) * 256], 16, 0, 0);
    };

    stage(0, i0);

    for (int cf = tid; cf < 384; cf += 256) {
        const int bl = cf / 48;
        const int rm = cf - bl * 48;
        float4 v = *reinterpret_cast<const float4*>(
            x + ((size_t)(bg * 8 + bl) * 1152 + i0) * 8 + rm * 4);
        *reinterpret_cast<float4*>(xs + bl * 192 + rm * 4) = v;
    }

    float Vr[2][8];
    if (R > 0) {
        #pragma unroll
        for (int bb = 0; bb < 2; ++bb) {
            const float* vp = Vacc + ((size_t)(b0 + bb) * 32 + j) * 16 + kh * 8;
            const float4 va = *reinterpret_cast<const float4*>(vp);
            const float4 vb = *reinterpret_cast<const float4*>(vp + 4);
            Vr[bb][0] = va.x * 1.44269504f; Vr[bb][1] = va.y * 1.44269504f;
            Vr[bb][2] = va.z * 1.44269504f; Vr[bb][3] = va.w * 1.44269504f;
            Vr[bb][4] = vb.x * 1.44269504f; Vr[bb][5] = vb.y * 1.44269504f;
            Vr[bb][6] = vb.z * 1.44269504f; Vr[bb][7] = vb.w * 1.44269504f;
        }
    }

    float sacc[2][8];
    #pragma unroll
    for (int bb = 0; bb < 2; ++bb)
        #pragma unroll
        for (int kk = 0; kk < 8; ++kk) sacc[bb][kk] = 0.0f;

    __syncthreads();

    const int sw = (j & 15) << 4;

    for (int ii = 0; ii < I_TILE_F; ++ii) {
        const int cur = ii & 1;
        if (ii + 1 < I_TILE_F) stage(cur ^ 1, i0 + ii + 1);

        float4 xa[2], xb[2];
        #pragma unroll
        for (int bb = 0; bb < 2; ++bb) {
            const float* xp = xs + (wv * 2 + bb) * 192 + ii * 8;
            xa[bb] = *reinterpret_cast<const float4*>(xp);
            xb[bb] = *reinterpret_cast<const float4*>(xp + 4);
        }

        const char* lbase = reinterpret_cast<const char*>(&Wt[cur][0]) + lane * 256;

        float u[2][8];
        #pragma unroll
        for (int kk = 0; kk < 8; ++kk) {
            const float4 w0 = *reinterpret_cast<const float4*>(lbase + ((kk * 32) ^ sw));
            const float4 w1 = *reinterpret_cast<const float4*>(lbase + ((kk * 32 + 16) ^ sw));
            #pragma unroll
            for (int bb = 0; bb < 2; ++bb) {
                float acc;
                acc = w0.x * xa[bb].x;
                acc = fmaf(w0.y, xa[bb].y, acc);
                acc = fmaf(w0.z, xa[bb].z, acc);
                acc = fmaf(w0.w, xa[bb].w, acc);
                acc = fmaf(w1.x, xb[bb].x, acc);
                acc = fmaf(w1.y, xb[bb].y, acc);
                acc = fmaf(w1.z, xb[bb].z, acc);
                acc = fmaf(w1.w, xb[bb].w, acc);
                u[bb][kk] = acc;
            }
        }

        if (R == 0) {
            #pragma unroll
            for (int bb = 0; bb < 2; ++bb)
                #pragma unroll
                for (int kk = 0; kk < 8; ++kk)
                    sacc[bb][kk] = fmaf(0.03125f, u[bb][kk], sacc[bb][kk]);
        } else {
            float p0 = u[0][0] * Vr[0][0];
            float p1 = u[1][0] * Vr[1][0];
            #pragma unroll
            for (int kk = 1; kk < 8; ++kk) {
                p0 = fmaf(u[0][kk], Vr[0][kk], p0);
                p1 = fmaf(u[1][kk], Vr[1][kk], p1);
            }
            p0 += __shfl_xor(p0, 32);
            p1 += __shfl_xor(p1, 32);
            const float pq = kh ? p1 : p0;
            const float e  = exp2f(pq);
            float den = e;
            den += __shfl_xor(den, 1);
            den += __shfl_xor(den, 2);
            den += __shfl_xor(den, 4);
            den += __shfl_xor(den, 8);
            den += __shfl_xor(den, 16);
            const float cf_own = e * __builtin_amdgcn_rcpf(den);
            const float cf_oth = __shfl_xor(cf_own, 32);
            const float cf0 = kh ? cf_oth : cf_own;
            const float cf1 = kh ? cf_own : cf_oth;
            #pragma unroll
            for (int kk = 0; kk < 8; ++kk) {
                sacc[0][kk] = fmaf(cf0, u[0][kk], sacc[0][kk]);
                sacc[1][kk] = fmaf(cf1, u[1][kk], sacc[1][kk]);
            }
        }
        __syncthreads();
    }

    {
        float* ep = &Wt[0][0] + wv * 1024;
        #pragma unroll
        for (int bb = 0; bb < 2; ++bb)
            #pragma unroll
            for (int kk = 0; kk < 8; ++kk)
                ep[bb * 512 + j * 16 + ((kh * 8 + kk) ^ ((j >> 1) & 15))] =
                    sacc[bb][kk];

        float* sg = s + (size_t)b0 * 512;
        #pragma unroll
        for (int c = 0; c < 16; ++c) {
            const int m   = c * 64 + lane;
            const int bb2 = m >> 9;
            const int j2  = (m >> 4) & 31;
            const int k2  = m & 15;
            const float v = ep[bb2 * 512 + j2 * 16 + (k2 ^ ((j2 >> 1) & 15))];
            atomicAdd(&sg[m], v);
        }
    }
}

// MODE 0: Vacc = v, zero s;  MODE 1: Vacc += v, zero s;  MODE 2: out = v
template<int MODE>
__global__ __launch_bounds__(256)
void caps_squash(float* __restrict__ s,
                 float* __restrict__ Vacc,
                 float* __restrict__ out)
{
    const int t = blockIdx.x * 256 + threadIdx.x;
    const float sv = s[t];
    float p = sv * sv;
    p += __shfl_xor(p, 1);
    p += __shfl_xor(p, 2);
    p += __shfl_xor(p, 4);
    p += __shfl_xor(p, 8);
    const float scale = p / ((1.0f + p) * sqrtf(p + 1e-7f));
    const float v = scale * sv;
    if (MODE == 0)      { Vacc[t] = v;  s[t] = 0.0f; }
    else if (MODE == 1) { Vacc[t] += v; s[t] = 0.0f; }
    else                { out[t] = v; }
}

extern "C" void kernel_launch(void* const* d_in, const int* in_sizes, int n_in,
                              void* d_out, int out_size, void* d_ws, size_t ws_size,
                              hipStream_t stream)
{
    const float* x = (const float*)d_in[0];   // [128,1152,8]
    const float* W = (const float*)d_in[1];   // [32,1152,16,8]
    float* out = (float*)d_out;               // [128,32,16]

    const size_t W2B = (size_t)1152 * 8192;   // 9,437,184 B bf16 tiles
    const size_t SB  = (size_t)65536 * sizeof(float);

    if (ws_size >= W2B + 2 * SB) {
        uint4* W2   = (uint4*)d_ws;
        float* Vacc = (float*)((char*)d_ws + W2B);
        float* sbuf = Vacc + 65536;
        const uint32_t* W2r = (const uint32_t*)d_ws;

        caps_prep<<<2304, 256, 0, stream>>>(W, W2);
        hipMemsetAsync(sbuf, 0, SB, stream);

        dim3 grid(16 * NSLICE);   // 1536 WGs
        dim3 blk(256);
        caps_route<0><<<grid, blk, 0, stream>>>(W2r, x, Vacc, sbuf);
        caps_squash<0><<<256, 256, 0, stream>>>(sbuf, Vacc, out);
        caps_route<1><<<grid, blk, 0, stream>>>(W2r, x, Vacc, sbuf);
        caps_squash<1><<<256, 256, 0, stream>>>(sbuf, Vacc, out);
        caps_route<2><<<grid, blk, 0, stream>>>(W2r, x, Vacc, sbuf);
        caps_squash<2><<<256, 256, 0, stream>>>(sbuf, Vacc, out);
    } else {
        float* Vacc = (float*)d_ws;
        float* sbuf = Vacc + 65536;
        hipMemsetAsync(sbuf, 0, SB, stream);

        dim3 grid(16 * NSLICE_F);  // 768 WGs
        dim3 blk(256);
        caps_route_f32<0><<<grid, blk, 0, stream>>>(x, W, Vacc, sbuf);
        caps_squash<0><<<256, 256, 0, stream>>>(sbuf, Vacc, out);
        caps_route_f32<1><<<grid, blk, 0, stream>>>(x, W, Vacc, sbuf);
        caps_squash<1><<<256, 256, 0, stream>>>(sbuf, Vacc, out);
        caps_route_f32<2><<<grid, blk, 0, stream>>>(x, W, Vacc, sbuf);
        caps_squash<2><<<256, 256, 0, stream>>>(sbuf, Vacc, out);
    }
}

// Round 10
// 115.687 us; speedup vs baseline: 1.4017x; 1.1832x over previous
//
#include <hip/hip_runtime.h>
#include <hip/hip_bf16.h>
#include <stdint.h>

// CapsuleLayer dynamic routing v10 — MFMA formulation.
// u_hat per i is a GEMM: U^T[(j,k), b] = W_i[(j,k), l] x^T[l, b].
// mfma_f32_16x16x32_bf16 per (j-tile, 16b): M=16 = the 16 k's of ONE j,
// N=16 b, K=32 (l=8 real, k-slots 8..31 zero-padded via zeroed A-frags —
// zero*anything = 0, so B's upper slots are don't-care).
// C layout (m89-verified): col=lane&15 = b, row=(lane>>4)*4+reg = k.
// => logits braw[b,j] = 4 FMA + shfl_xor(16)+shfl_xor(32); V and c are
// lane-local. WG = 8 waves = 16 b x all 32 j; K-loop over 18 i.
// W/x read as bf16 frags DIRECT from L2 (no LDS staging, no stage barriers);
// prep kernels lay out W3 [i][j][k][l] and x2T [i][b][l] once per launch.
// Softmax: one barrier/i (8x16 partial-denominator exchange, double-buffered).
// Epilogue: v6-proven per-wave LDS transpose -> 64-contiguous atomics.

using fab = __attribute__((ext_vector_type(8))) short;   // 8 bf16 = 4 VGPR
using fcc = __attribute__((ext_vector_type(4))) float;   // 4 f32 accum

__device__ __forceinline__ uint32_t bfr(float f) {   // fp32 -> bf16 RTN-even
    uint32_t u = __float_as_uint(f);
    return (u + 0x7fffu + ((u >> 16) & 1u)) >> 16;
}

// W3[((i*32 + j)*16 + k)*8 + l] bf16  (16B per (i,j,k) row)
__global__ __launch_bounds__(256)
void prep_w(const float* __restrict__ W, ushort* __restrict__ W3)
{
    const int t = blockIdx.x * 256 + threadIdx.x;   // (i,j,k), k fastest
    const int k = t & 15, j = (t >> 4) & 31, i = t >> 9;
    const float* src = W + (((size_t)j * 1152 + i) * 16 + k) * 8;
    const float4 a = *reinterpret_cast<const float4*>(src);
    const float4 b = *reinterpret_cast<const float4*>(src + 4);
    uint4 o;
    o.x = bfr(a.x) | (bfr(a.y) << 16);
    o.y = bfr(a.z) | (bfr(a.w) << 16);
    o.z = bfr(b.x) | (bfr(b.y) << 16);
    o.w = bfr(b.z) | (bfr(b.w) << 16);
    *reinterpret_cast<uint4*>(W3 + (size_t)t * 8) = o;
}

// x2T[(i*128 + b)*8 + l] bf16
__global__ __launch_bounds__(256)
void prep_x(const float* __restrict__ x, ushort* __restrict__ X2)
{
    const int t = blockIdx.x * 256 + threadIdx.x;   // (i,b), b fastest
    const int b = t & 127, i = t >> 7;
    const float* src = x + ((size_t)b * 1152 + i) * 8;
    const float4 a = *reinterpret_cast<const float4*>(src);
    const float4 bb = *reinterpret_cast<const float4*>(src + 4);
    uint4 o;
    o.x = bfr(a.x) | (bfr(a.y) << 16);
    o.y = bfr(a.z) | (bfr(a.w) << 16);
    o.z = bfr(bb.x) | (bfr(bb.y) << 16);
    o.w = bfr(bb.z) | (bfr(bb.w) << 16);
    *reinterpret_cast<uint4*>(X2 + (size_t)t * 8) = o;
}

template<int R>
__global__ __launch_bounds__(512)
void caps_route_mfma(const ushort* __restrict__ W3,
                     const ushort* __restrict__ X2,
                     const float* __restrict__ Vacc,
                     float* __restrict__ s)      // [128,32,16] zeroed
{
    __shared__ float pl[2][8][16];   // per-wave softmax partial denoms, dbuf
    __shared__ float tr[8][1024];    // per-wave transpose buffers (32KB)

    const int tid  = threadIdx.x;
    const int lane = tid & 63;
    const int w    = tid >> 6;       // wave 0..7 -> j-tiles w*4..w*4+3
    const int bl   = lane & 15;      // A: k-row ; B: b-col ; C: b-col
    const int kg   = lane >> 4;      // k-slot group (C rows kg*4..kg*4+3)
    const bool lo  = (kg == 0);      // lanes with real K-slots (l = 0..7)
    const int bg   = blockIdx.x >> 6;    // 0..7 batch group
    const int sl   = blockIdx.x & 63;    // i-slice
    const int i0   = sl * 18;
    const int b0   = bg * 16;

    fab zf;
    #pragma unroll
    for (int q = 0; q < 8; ++q) zf[q] = 0;

    auto loadA = [&](int i, int t) -> fab {
        return lo ? *reinterpret_cast<const fab*>(
                        W3 + (((size_t)i * 32 + w * 4 + t) * 16 + bl) * 8)
                  : zf;
    };
    auto loadB = [&](int i) -> fab {
        return lo ? *reinterpret_cast<const fab*>(
                        X2 + ((size_t)i * 128 + b0 + bl) * 8)
                  : zf;
    };

    // Vacc fragment (i-independent, lane-local), log2 domain
    float Vr[4][4];
    if (R > 0) {
        #pragma unroll
        for (int t = 0; t < 4; ++t)
            #pragma unroll
            for (int r = 0; r < 4; ++r)
                Vr[t][r] = Vacc[((size_t)(b0 + bl) * 32 + w * 4 + t) * 16
                                + kg * 4 + r] * 1.44269504f;
    }

    fcc sacc[4];
    #pragma unroll
    for (int t = 0; t < 4; ++t)
        #pragma unroll
        for (int r = 0; r < 4; ++r) sacc[t][r] = 0.0f;

    auto body = [&](const fab* A, const fab& B, int ii) {
        const fcc cz = {0.0f, 0.0f, 0.0f, 0.0f};
        fcc u[4];
        #pragma unroll
        for (int t = 0; t < 4; ++t)
            u[t] = __builtin_amdgcn_mfma_f32_16x16x32_bf16(A[t], B, cz, 0, 0, 0);

        float cf4[4];
        if (R == 0) {
            #pragma unroll
            for (int t = 0; t < 4; ++t) cf4[t] = 0.03125f;
        } else {
            float e[4];
            float ps = 0.0f;
            #pragma unroll
            for (int t = 0; t < 4; ++t) {
                float p = u[t][0] * Vr[t][0];
                p = fmaf(u[t][1], Vr[t][1], p);
                p = fmaf(u[t][2], Vr[t][2], p);
                p = fmaf(u[t][3], Vr[t][3], p);
                p += __shfl_xor(p, 16);          // combine k-groups
                p += __shfl_xor(p, 32);
                e[t] = exp2f(p);                 // no max-subtract: |p| small
                ps += e[t];
            }
            const int ib = ii & 1;
            if (lane < 16) pl[ib][w][bl] = ps;
            __syncthreads();
            float den = pl[ib][0][bl];
            #pragma unroll
            for (int ww = 1; ww < 8; ++ww) den += pl[ib][ww][bl];
            const float inv = __builtin_amdgcn_rcpf(den);
            #pragma unroll
            for (int t = 0; t < 4; ++t) cf4[t] = e[t] * inv;
        }
        #pragma unroll
        for (int t = 0; t < 4; ++t)
            #pragma unroll
            for (int r = 0; r < 4; ++r)
                sacc[t][r] = fmaf(cf4[t], u[t][r], sacc[t][r]);
    };

    // distance-1 register prefetch, unroll-2 (18 iters, even)
    fab A0[4], A1[4], B0, B1;
    #pragma unroll
    for (int t = 0; t < 4; ++t) A0[t] = loadA(i0, t);
    B0 = loadB(i0);

    for (int ii = 0; ii < 18; ii += 2) {
        {
            const int ip = i0 + ii + 1;
            #pragma unroll
            for (int t = 0; t < 4; ++t) A1[t] = loadA(ip, t);
            B1 = loadB(ip);
        }
        body(A0, B0, ii);
        {
            int ip = i0 + ii + 2;
            if (ip > 1151) ip = 1151;            // clamp (last prefetch unused)
            #pragma unroll
            for (int t = 0; t < 4; ++t) A0[t] = loadA(ip, t);
            B0 = loadB(ip);
        }
        body(A1, B1, ii + 1);
    }

    // ---- epilogue: per-wave LDS transpose -> 64-contiguous atomics ----
    // sacc[t][r] = s-partial[b0+bl][j=w*4+t][k=kg*4+r]; off = t*16+kg*4+r.
    // DS ops are in-order per wave (v6-proven) -> no barrier needed.
    {
        float* ep = &tr[w][0];
        #pragma unroll
        for (int t = 0; t < 4; ++t)
            #pragma unroll
            for (int r = 0; r < 4; ++r) {
                const int off = t * 16 + kg * 4 + r;
                ep[off * 16 + (bl ^ (off & 15))] = sacc[t][r];
            }
        float* sg = s + (size_t)b0 * 512 + w * 64;
        #pragma unroll
        for (int c = 0; c < 16; ++c) {
            const float v = ep[lane * 16 + (c ^ (lane & 15))];
            atomicAdd(&sg[(size_t)c * 512 + lane], v);   // 64 contiguous
        }
    }
}

// ==================== fp32 fallback route (v6 verbatim) ====================
#define WJ        (1152 * 128)
#define I_TILE_F  24
#define NSLICE_F  48

template<int R>
__global__ __launch_bounds__(256)
void caps_route_f32(const float* __restrict__ x,
                    const float* __restrict__ W,
                    const float* __restrict__ Vacc,
                    float* __restrict__ s)
{
    __shared__ float Wt[2][4096];
    __shared__ float xs[8 * 192];

    const int tid  = threadIdx.x;
    const int lane = tid & 63;
    const int wv   = tid >> 6;
    const int j    = lane & 31;
    const int kh   = lane >> 5;
    const int bg   = blockIdx.x / NSLICE_F;
    const int sl   = blockIdx.x % NSLICE_F;
    const int i0   = sl * I_TILE_F;
    const int b0   = bg * 8 + wv * 2;

    const float* wsrc[4];
    #pragma unroll
    for (int t = 0; t < 4; ++t) {
        const int q  = (wv * 4 + t) * 1024 + lane * 16;
        const int rr = q >> 8;
        const int cb = (q & 255) ^ ((rr & 15) << 4);
        const int js = rr & 31;
        const int c  = (rr >> 5) * 64 + (cb >> 2);
        wsrc[t] = W + (size_t)js * WJ + c;
    }

    auto stage = [&](int buf, int i) {
        #pragma unroll
        for (int t = 0; t < 4; ++t)
            __builtin_amdgcn_global_load_lds(
                (const __attribute__((address_space(1))) uint32_t*)
                    (wsrc[t] + (size_t)i * 128),
                (__attribute__((address_space(3))) uint32_t*)
                    &Wt[buf][(wv * 4 + t) * 256], 16, 0, 0);
    };

    stage(0, i0);

    for (int cf = tid; cf < 384; cf += 256) {
        const int bl = cf / 48;
        const int rm = cf - bl * 48;
        float4 v = *reinterpret_cast<const float4*>(
            x + ((size_t)(bg * 8 + bl) * 1152 + i0) * 8 + rm * 4);
        *reinterpret_cast<float4*>(xs + bl * 192 + rm * 4) = v;
    }

    float Vr[2][8];
    if (R > 0) {
        #pragma unroll
        for (int bb = 0; bb < 2; ++bb) {
            const float* vp = Vacc + ((size_t)(b0 + bb) * 32 + j) * 16 + kh * 8;
            const float4 va = *reinterpret_cast<const float4*>(vp);
            const float4 vb = *reinterpret_cast<const float4*>(vp + 4);
            Vr[bb][0] = va.x * 1.44269504f; Vr[bb][1] = va.y * 1.44269504f;
            Vr[bb][2] = va.z * 1.44269504f; Vr[bb][3] = va.w * 1.44269504f;
            Vr[bb][4] = vb.x * 1.44269504f; Vr[bb][5] = vb.y * 1.44269504f;
            Vr[bb][6] = vb.z * 1.44269504f; Vr[bb][7] = vb.w * 1.44269504f;
        }
    }

    float sacc[2][8];
    #pragma unroll
    for (int bb = 0; bb < 2; ++bb)
        #pragma unroll
        for (int kk = 0; kk < 8; ++kk) sacc[bb][kk] = 0.0f;

    __syncthreads();

    const int sw = (j & 15) << 4;

    for (int ii = 0; ii < I_TILE_F; ++ii) {
        const int cur = ii & 1;
        if (ii + 1 < I_TILE_F) stage(cur ^ 1, i0 + ii + 1);

        float4 xa[2], xb[2];
        #pragma unroll
        for (int bb = 0; bb < 2; ++bb) {
            const float* xp = xs + (wv * 2 + bb) * 192 + ii * 8;
            xa[bb] = *reinterpret_cast<const float4*>(xp);
            xb[bb] = *reinterpret_cast<const float4*>(xp + 4);
        }

        const char* lbase = reinterpret_cast<const char*>(&Wt[cur][0]) + lane * 256;

        float u[2][8];
        #pragma unroll
        for (int kk = 0; kk < 8; ++kk) {
            const float4 w0 = *reinterpret_cast<const float4*>(lbase + ((kk * 32) ^ sw));
            const float4 w1 = *reinterpret_cast<const float4*>(lbase + ((kk * 32 + 16) ^ sw));
            #pragma unroll
            for (int bb = 0; bb < 2; ++bb) {
                float acc;
                acc = w0.x * xa[bb].x;
                acc = fmaf(w0.y, xa[bb].y, acc);
                acc = fmaf(w0.z, xa[bb].z, acc);
                acc = fmaf(w0.w, xa[bb].w, acc);
                acc = fmaf(w1.x, xb[bb].x, acc);
                acc = fmaf(w1.y, xb[bb].y, acc);
                acc = fmaf(w1.z, xb[bb].z, acc);
                acc = fmaf(w1.w, xb[bb].w, acc);
                u[bb][kk] = acc;
            }
        }

        if (R == 0) {
            #pragma unroll
            for (int bb = 0; bb < 2; ++bb)
                #pragma unroll
                for (int kk = 0; kk < 8; ++kk)
                    sacc[bb][kk] = fmaf(0.03125f, u[bb][kk], sacc[bb][kk]);
        } else {
            float p0 = u[0][0] * Vr[0][0];
            float p1 = u[1][0] * Vr[1][0];
            #pragma unroll
            for (int kk = 1; kk < 8; ++kk) {
                p0 = fmaf(u[0][kk], Vr[0][kk], p0);
                p1 = fmaf(u[1][kk], Vr[1][kk], p1);
            }
            p0 += __shfl_xor(p0, 32);
            p1 += __shfl_xor(p1, 32);
            const float pq = kh ? p1 : p0;
            const float e  = exp2f(pq);
            float den = e;
            den += __shfl_xor(den, 1);
            den += __shfl_xor(den, 2);
            den += __shfl_xor(den, 4);
            den += __shfl_xor(den, 8);
            den += __shfl_xor(den, 16);
            const float cf_own = e * __builtin_amdgcn_rcpf(den);
            const float cf_oth = __shfl_xor(cf_own, 32);
            const float cf0 = kh ? cf_oth : cf_own;
            const float cf1 = kh ? cf_own : cf_oth;
            #pragma unroll
            for (int kk = 0; kk < 8; ++kk) {
                sacc[0][kk] = fmaf(cf0, u[0][kk], sacc[0][kk]);
                sacc[1][kk] = fmaf(cf1, u[1][kk], sacc[1][kk]);
            }
        }
        __syncthreads();
    }

    {
        float* ep = &Wt[0][0] + wv * 1024;
        #pragma unroll
        for (int bb = 0; bb < 2; ++bb)
            #pragma unroll
            for (int kk = 0; kk < 8; ++kk)
                ep[bb * 512 + j * 16 + ((kh * 8 + kk) ^ ((j >> 1) & 15))] =
                    sacc[bb][kk];

        float* sg = s + (size_t)b0 * 512;
        #pragma unroll
        for (int c = 0; c < 16; ++c) {
            const int m   = c * 64 + lane;
            const int bb2 = m >> 9;
            const int j2  = (m >> 4) & 31;
            const int k2  = m & 15;
            const float v = ep[bb2 * 512 + j2 * 16 + (k2 ^ ((j2 >> 1) & 15))];
            atomicAdd(&sg[m], v);
        }
    }
}

// MODE 0: Vacc = v, zero s;  MODE 1: Vacc += v, zero s;  MODE 2: out = v
template<int MODE>
__global__ __launch_bounds__(256)
void caps_squash(float* __restrict__ s,
                 float* __restrict__ Vacc,
                 float* __restrict__ out)
{
    const int t = blockIdx.x * 256 + threadIdx.x;   // (b,j,k), k fastest
    const float sv = s[t];
    float p = sv * sv;
    p += __shfl_xor(p, 1);
    p += __shfl_xor(p, 2);
    p += __shfl_xor(p, 4);
    p += __shfl_xor(p, 8);
    const float scale = p / ((1.0f + p) * sqrtf(p + 1e-7f));
    const float v = scale * sv;
    if (MODE == 0)      { Vacc[t] = v;  s[t] = 0.0f; }
    else if (MODE == 1) { Vacc[t] += v; s[t] = 0.0f; }
    else                { out[t] = v; }
}

extern "C" void kernel_launch(void* const* d_in, const int* in_sizes, int n_in,
                              void* d_out, int out_size, void* d_ws, size_t ws_size,
                              hipStream_t stream)
{
    const float* x = (const float*)d_in[0];   // [128,1152,8]
    const float* W = (const float*)d_in[1];   // [32,1152,16,8]
    float* out = (float*)d_out;               // [128,32,16]

    const size_t W3B = (size_t)589824 * 16;   // 9,437,184 B
    const size_t X2B = (size_t)147456 * 16;   // 2,359,296 B
    const size_t SB  = (size_t)65536 * sizeof(float);

    if (ws_size >= W3B + X2B + 2 * SB) {
        ushort* W3  = (ushort*)d_ws;
        ushort* X2  = (ushort*)((char*)d_ws + W3B);
        float* Vacc = (float*)((char*)d_ws + W3B + X2B);
        float* sbuf = Vacc + 65536;

        prep_w<<<2304, 256, 0, stream>>>(W, (ushort*)W3);
        prep_x<<<576, 256, 0, stream>>>(x, (ushort*)X2);
        hipMemsetAsync(sbuf, 0, SB, stream);

        dim3 grid(512);    // 8 bgroups x 64 i-slices = 2 WG/CU (512 thr)
        dim3 blk(512);
        caps_route_mfma<0><<<grid, blk, 0, stream>>>(W3, X2, Vacc, sbuf);
        caps_squash<0><<<256, 256, 0, stream>>>(sbuf, Vacc, out);
        caps_route_mfma<1><<<grid, blk, 0, stream>>>(W3, X2, Vacc, sbuf);
        caps_squash<1><<<256, 256, 0, stream>>>(sbuf, Vacc, out);
        caps_route_mfma<2><<<grid, blk, 0, stream>>>(W3, X2, Vacc, sbuf);
        caps_squash<2><<<256, 256, 0, stream>>>(sbuf, Vacc, out);
    } else {
        float* Vacc = (float*)d_ws;
        float* sbuf = Vacc + 65536;
        hipMemsetAsync(sbuf, 0, SB, stream);

        dim3 grid(16 * NSLICE_F);  // 768 WGs
        dim3 blk(256);
        caps_route_f32<0><<<grid, blk, 0, stream>>>(x, W, Vacc, sbuf);
        caps_squash<0><<<256, 256, 0, stream>>>(sbuf, Vacc, out);
        caps_route_f32<1><<<grid, blk, 0, stream>>>(x, W, Vacc, sbuf);
        caps_squash<1><<<256, 256, 0, stream>>>(sbuf, Vacc, out);
        caps_route_f32<2><<<grid, blk, 0, stream>>>(x, W, Vacc, sbuf);
        caps_squash<2><<<256, 256, 0, stream>>>(sbuf, Vacc, out);
    }
}